// Round 10
// baseline (862.794 us; speedup 1.0000x reference)
//
#include <hip/hip_runtime.h>
#include <hip/hip_bf16.h>

// PairWeightedAveraging. S=T=512, CM=64, CZ=128, H=8, D=32.
// ws: wb bf16[8*512*512] (4MB) | vbT bf16[256][262144] (128MB) |
//     ob bf16[262144*256] (128MB) | WoT bf16[64][256] (32KB)
// Pipeline: k_weights -> wb ; k_vproj -> vbT (V^T, j contig) ; k_pairavg (MFMA) -> ob ;
//           k_gate (LN+sigmoid gemm, in-place bf16) ; k_wot -> WoT ; k_out (MFMA) -> out.
// Audit trail: r3 gload_lds layout + swizzle involution + MFMA algebra + dataflow;
// r4 ob->bf16; r5 k_out MFMA; r6 k_out audit + tr-stride analysis; r7 bank-group
// bijectivity; r8 LDS budget/index bounds/capture rules; r9 intra-wave LDS RAW
// ordering (in-order DS retire + compiler must-alias) — audit closed.

#define EPS 1e-5f

constexpr int S = 512, T = 512, CM = 64, CZ = 128, H = 8, D = 32;
constexpr int HD = H * D;            // 256
constexpr size_t ST = (size_t)S * T; // 262144

typedef unsigned short u16;
typedef unsigned int   u32;
typedef __attribute__((ext_vector_type(8))) short s16x8;
typedef __attribute__((ext_vector_type(4))) float f32x4;

__device__ __forceinline__ u16 f2bf(float f) {
    u32 x = __builtin_bit_cast(u32, f);
    return (u16)((x + 0x7FFFu + ((x >> 16) & 1u)) >> 16); // RNE
}
__device__ __forceinline__ float bf2f(u16 v) {
    u32 x = ((u32)v) << 16;
    return __builtin_bit_cast(float, x);
}

__device__ __forceinline__ void async16(void* lds, const void* g) {
    __builtin_amdgcn_global_load_lds(
        (const __attribute__((address_space(1))) u32*)g,
        (__attribute__((address_space(3))) u32*)lds, 16, 0, 0);
}

// ---------------------------------------------------------------------------
// Kernel 1: z -> softmax weights, bf16: wb[h][i][j]. One block per i.
// ---------------------------------------------------------------------------
__global__ __launch_bounds__(256) void k_weights(
    const float* __restrict__ z, const float* __restrict__ zw,
    const float* __restrict__ zb, const float* __restrict__ Wz,
    u16* __restrict__ wb)
{
    __shared__ float Wz_lds[CZ][H];
    __shared__ float b_lds[H][T + 4];
    __shared__ float zn_lds[4][8][CZ + 4];

    const int i    = blockIdx.x;
    const int t    = threadIdx.x;
    const int lane = t & 63, wave = t >> 6;

    for (int f = t; f < CZ * H; f += 256)
        Wz_lds[f / H][f % H] = Wz[f];
    __syncthreads();

    const float zw0 = zw[2 * lane], zw1 = zw[2 * lane + 1];
    const float zb0 = zb[2 * lane], zb1 = zb[2 * lane + 1];

    for (int chunk = 0; chunk < 16; ++chunk) {
        const int jbase = wave * 128 + chunk * 8;
        for (int jj = 0; jj < 8; ++jj) {
            const int j = jbase + jj;
            const float2 x = *reinterpret_cast<const float2*>(
                &z[((size_t)i * T + j) * CZ + 2 * lane]);
            float s1 = x.x + x.y;
            float s2 = x.x * x.x + x.y * x.y;
            #pragma unroll
            for (int mm = 32; mm >= 1; mm >>= 1) {
                s1 += __shfl_xor(s1, mm);
                s2 += __shfl_xor(s2, mm);
            }
            const float mu  = s1 * (1.0f / CZ);
            const float var = s2 * (1.0f / CZ) - mu * mu;
            const float rs  = rsqrtf(var + EPS);
            zn_lds[wave][jj][2 * lane]     = (x.x - mu) * rs * zw0 + zb0;
            zn_lds[wave][jj][2 * lane + 1] = (x.y - mu) * rs * zw1 + zb1;
        }
        // intra-wave LDS RAW: DS pipe retires same-wave ops in order (r9 audit);
        // per-wave zn_lds partition removes cross-wave hazards.
        const int jloc = lane >> 3, h = lane & 7;
        float acc = 0.f;
        #pragma unroll 8
        for (int c = 0; c < CZ; ++c)
            acc += zn_lds[wave][jloc][c] * Wz_lds[c][h];
        b_lds[h][jbase + jloc] = acc;
    }
    __syncthreads();

    for (int hh = 0; hh < 2; ++hh) {
        const int h = wave * 2 + hh;
        float bv[8];
        float mx = -1e30f;
        #pragma unroll
        for (int q = 0; q < 8; ++q) {
            bv[q] = b_lds[h][lane + 64 * q];
            mx = fmaxf(mx, bv[q]);
        }
        #pragma unroll
        for (int mm = 32; mm >= 1; mm >>= 1)
            mx = fmaxf(mx, __shfl_xor(mx, mm));
        float sum = 0.f;
        #pragma unroll
        for (int q = 0; q < 8; ++q) {
            bv[q] = __expf(bv[q] - mx);
            sum += bv[q];
        }
        #pragma unroll
        for (int mm = 32; mm >= 1; mm >>= 1)
            sum += __shfl_xor(sum, mm);
        const float inv = 1.0f / sum;
        u16* wp = &wb[((size_t)h * T + i) * T];
        #pragma unroll
        for (int q = 0; q < 8; ++q)
            wp[lane + 64 * q] = f2bf(bv[q] * inv);
    }
}

// ---------------------------------------------------------------------------
// Kernel 2: LN(m) @ Wm -> vbT[h*32+d][s*512+j] bf16 (V transposed, j contig).
// Phase 1: fp32 tile GEMM. Phase 2: LDS transpose to bf16. Row stride 136 u16
// (= 272B): the only 16B-aligned stride that keeps the float4 read phase legal;
// write-phase 8-way conflict accepted (evaluated alternatives r6).
// ---------------------------------------------------------------------------
__global__ __launch_bounds__(256) void k_vproj(
    const float* __restrict__ m, const float* __restrict__ nw,
    const float* __restrict__ nb, const float* __restrict__ W,
    u16* __restrict__ vbT)
{
    __shared__ float smraw[64 * 132 + 64 * 128]; // A_lds | W_lds ; tr overlays (65KB, OK on gfx950)
    float (*A_lds)[132] = (float(*)[132])smraw;
    float (*W_lds)[128] = (float(*)[128])(smraw + 64 * 132);

    const int t    = threadIdx.x;
    const int lane = t & 63, wave = t >> 6;
    const size_t row0 = (size_t)blockIdx.x * 128;
    const int colbase = blockIdx.y * 128;

    #pragma unroll
    for (int rep = 0; rep < 8; ++rep) {
        const int f4 = t + 256 * rep;
        const int c = f4 >> 5, n4 = f4 & 31;
        *reinterpret_cast<float4*>(&W_lds[c][n4 * 4]) =
            *reinterpret_cast<const float4*>(&W[c * HD + colbase + n4 * 4]);
    }

    const float nwc = nw[lane], nbc = nb[lane];
    for (int rr = 0; rr < 32; ++rr) {
        const int rloc = wave * 32 + rr;
        const float x = m[(row0 + rloc) * CM + lane];
        float s1 = x, s2 = x * x;
        #pragma unroll
        for (int mm = 32; mm >= 1; mm >>= 1) {
            s1 += __shfl_xor(s1, mm);
            s2 += __shfl_xor(s2, mm);
        }
        const float mu  = s1 * (1.0f / CM);
        const float var = s2 * (1.0f / CM) - mu * mu;
        const float rs  = rsqrtf(var + EPS);
        A_lds[lane][rloc] = (x - mu) * rs * nwc + nbc;
    }
    __syncthreads();

    const int mi0 = (t >> 4) * 4;  // j-local {mi0..+3} U {+64}
    const int nj0 = (t & 15) * 4;  // c-local {nj0..+3} U {+64}
    float acc[8][8] = {};

    #pragma unroll 8
    for (int k = 0; k < CM; ++k) {
        float a[8], b[8];
        *reinterpret_cast<float4*>(&a[0]) = *reinterpret_cast<const float4*>(&A_lds[k][mi0]);
        *reinterpret_cast<float4*>(&a[4]) = *reinterpret_cast<const float4*>(&A_lds[k][mi0 + 64]);
        *reinterpret_cast<float4*>(&b[0]) = *reinterpret_cast<const float4*>(&W_lds[k][nj0]);
        *reinterpret_cast<float4*>(&b[4]) = *reinterpret_cast<const float4*>(&W_lds[k][nj0 + 64]);
        #pragma unroll
        for (int r = 0; r < 8; ++r)
            #pragma unroll
            for (int c = 0; c < 8; ++c)
                acc[r][c] += a[r] * b[c];
    }

    // ---- phase 2: transpose to bf16 via LDS (reuse smraw), write vbT ----
    __syncthreads();
    u16 (*tr)[136] = (u16(*)[136])smraw; // 128 x 136 u16; 272B rows

    #pragma unroll
    for (int cb = 0; cb < 2; ++cb)
      #pragma unroll
      for (int cc = 0; cc < 4; ++cc) {
        const int c = nj0 + cb * 64 + cc;
        #pragma unroll
        for (int rb = 0; rb < 2; ++rb) {
            ushort4 v;
            v.x = f2bf(acc[rb * 4 + 0][cb * 4 + cc]);
            v.y = f2bf(acc[rb * 4 + 1][cb * 4 + cc]);
            v.z = f2bf(acc[rb * 4 + 2][cb * 4 + cc]);
            v.w = f2bf(acc[rb * 4 + 3][cb * 4 + cc]);
            *reinterpret_cast<ushort4*>(&tr[c][mi0 + rb * 64]) = v;
        }
      }
    __syncthreads();

    const int c2 = t >> 1, half = t & 1;
    const size_t dstb = (size_t)(colbase + c2) * ST + row0 + half * 64;
    #pragma unroll
    for (int q = 0; q < 8; ++q) {
        const float4 v = *reinterpret_cast<const float4*>(&tr[c2][half * 64 + q * 8]);
        *reinterpret_cast<float4*>(&vbT[dstb + q * 8]) = v;
    }
}

// ---------------------------------------------------------------------------
// Kernel 3: per-head bf16 MFMA GEMM  D[i][n=(s,d)] = sum_j w[i,j] * vT[n,j].
// Tile 128(i) x 128(n), BK=32, 4 waves (2x2, each 64x64 = 4x4 frags 16x16).
// Operand LDS: [row][32 k] bf16, 64B rows, XOR swizzle ((r>>1)&3)<<4 bytes,
// staged linear via global_load_lds with pre-swizzled per-lane source (G21).
// Grid (128 n-tiles, 4 i-tiles, 8 heads). Output bf16.
// ---------------------------------------------------------------------------
__global__ __launch_bounds__(256) void k_pairavg(
    const u16* __restrict__ wb, const u16* __restrict__ vbT,
    u16* __restrict__ ob)
{
    __shared__ u16 Abuf[2][128 * 32]; // 8KB each buf
    __shared__ u16 Bbuf[2][128 * 32];

    const int t    = threadIdx.x;
    const int lane = t & 63, wave = t >> 6;
    const int n0 = blockIdx.x * 128;
    const int i0 = blockIdx.y * 128;
    const int h  = blockIdx.z;
    const int wr = wave >> 1, wc = wave & 1;

    // staging: instr g = wave*2+q covers rows r = g*16 + (lane>>2), chunk c4 = lane&3
    const int rQ0 = wave * 32 + (lane >> 2);
    const int c4  = lane & 3;
    const int s0  = n0 >> 5;
    const size_t wbase = ((size_t)h * T + i0) * T;

    f32x4 acc[4][4];
    #pragma unroll
    for (int a = 0; a < 4; ++a)
        #pragma unroll
        for (int b = 0; b < 4; ++b)
            acc[a][b] = (f32x4){0.f, 0.f, 0.f, 0.f};

#define STAGE(BUF, KT) do {                                                     \
    const int j0_ = (KT) * 32;                                                  \
    _Pragma("unroll")                                                           \
    for (int q = 0; q < 2; ++q) {                                               \
        const int r  = rQ0 + q * 16;                                            \
        const int e  = (c4 * 8) ^ (((r >> 1) & 3) << 3); /* swizzled k-elems */ \
        async16(&Abuf[BUF][(wave * 2 + q) * 512],                               \
                &wb[wbase + (size_t)r * T + j0_ + e]);                          \
        const int sB = s0 + (r >> 5), dB = r & 31;                              \
        async16(&Bbuf[BUF][(wave * 2 + q) * 512],                               \
                &vbT[(size_t)(h * 32 + dB) * ST + (size_t)sB * T + j0_ + e]);   \
    }                                                                           \
} while (0)

    STAGE(0, 0);
    __syncthreads();
    int cur = 0;

    for (int kt = 0; kt < 16; ++kt) {
        if (kt < 15) STAGE(cur ^ 1, kt + 1);

        s16x8 af[4], bfr[4];
        #pragma unroll
        for (int f = 0; f < 4; ++f) {
            const int r  = wr * 64 + f * 16 + (lane & 15);
            af[f] = *reinterpret_cast<const s16x8*>(
                &Abuf[cur][r * 32 + (((lane >> 4) * 8) ^ (((r >> 1) & 3) << 3))]);
            const int rn = wc * 64 + f * 16 + (lane & 15);
            bfr[f] = *reinterpret_cast<const s16x8*>(
                &Bbuf[cur][rn * 32 + (((lane >> 4) * 8) ^ (((rn >> 1) & 3) << 3))]);
        }
        #pragma unroll
        for (int fm = 0; fm < 4; ++fm)
            #pragma unroll
            for (int fn = 0; fn < 4; ++fn)
                acc[fm][fn] = __builtin_amdgcn_mfma_f32_16x16x32_bf16(
                    af[fm], bfr[fn], acc[fm][fn], 0, 0, 0);

        __syncthreads(); // drains vmcnt(0): prefetch for cur^1 is complete here
        cur ^= 1;
    }
#undef STAGE

    // C/D: col(lane&15) = n-offset, row((lane>>4)*4+reg) = i-offset (m89).
    #pragma unroll
    for (int fm = 0; fm < 4; ++fm) {
        const int i_g = i0 + wr * 64 + fm * 16 + ((lane >> 4) << 2);
        #pragma unroll
        for (int fn = 0; fn < 4; ++fn) {
            const int n_g = n0 + wc * 64 + fn * 16 + (lane & 15);
            const int s = n_g >> 5, d = n_g & 31;
            u16* dst = &ob[(((size_t)s * T + i_g) * H + h) * D + d];
            #pragma unroll
            for (int r = 0; r < 4; ++r)
                dst[(size_t)r * HD] = f2bf(acc[fm][fn][r]); // i+1 -> +256 elems
        }
    }
}

// ---------------------------------------------------------------------------
// Kernel 4: gate — ob *= sigmoid(LN(m) @ Wg), in place, bf16 RMW.
// ---------------------------------------------------------------------------
__global__ __launch_bounds__(256) void k_gate(
    const float* __restrict__ m, const float* __restrict__ nw,
    const float* __restrict__ nb, const float* __restrict__ W,
    u16* __restrict__ out)
{
    __shared__ float A_lds[CM][128 + 4];
    __shared__ float W_lds[CM][128];

    const int t    = threadIdx.x;
    const int lane = t & 63, wave = t >> 6;
    const size_t row0 = (size_t)blockIdx.x * 128;
    const int colbase = blockIdx.y * 128;

    #pragma unroll
    for (int rep = 0; rep < 8; ++rep) {
        const int f4 = t + 256 * rep;
        const int c = f4 >> 5, n4 = f4 & 31;
        *reinterpret_cast<float4*>(&W_lds[c][n4 * 4]) =
            *reinterpret_cast<const float4*>(&W[c * HD + colbase + n4 * 4]);
    }

    const float nwc = nw[lane], nbc = nb[lane];
    for (int rr = 0; rr < 32; ++rr) {
        const int rloc = wave * 32 + rr;
        const float x = m[(row0 + rloc) * CM + lane];
        float s1 = x, s2 = x * x;
        #pragma unroll
        for (int mm = 32; mm >= 1; mm >>= 1) {
            s1 += __shfl_xor(s1, mm);
            s2 += __shfl_xor(s2, mm);
        }
        const float mu  = s1 * (1.0f / CM);
        const float var = s2 * (1.0f / CM) - mu * mu;
        const float rs  = rsqrtf(var + EPS);
        A_lds[lane][rloc] = (x - mu) * rs * nwc + nbc;
    }
    __syncthreads();

    const int mi0 = (t >> 4) * 4;
    const int nj0 = (t & 15) * 4;
    float acc[8][8] = {};

    #pragma unroll 8
    for (int k = 0; k < CM; ++k) {
        float a[8], b[8];
        *reinterpret_cast<float4*>(&a[0]) = *reinterpret_cast<const float4*>(&A_lds[k][mi0]);
        *reinterpret_cast<float4*>(&a[4]) = *reinterpret_cast<const float4*>(&A_lds[k][mi0 + 64]);
        *reinterpret_cast<float4*>(&b[0]) = *reinterpret_cast<const float4*>(&W_lds[k][nj0]);
        *reinterpret_cast<float4*>(&b[4]) = *reinterpret_cast<const float4*>(&W_lds[k][nj0 + 64]);
        #pragma unroll
        for (int r = 0; r < 8; ++r)
            #pragma unroll
            for (int c = 0; c < 8; ++c)
                acc[r][c] += a[r] * b[c];
    }

    #pragma unroll
    for (int rb = 0; rb < 2; ++rb)
      #pragma unroll
      for (int rr = 0; rr < 4; ++rr) {
        const size_t row = row0 + mi0 + rb * 64 + rr;
        #pragma unroll
        for (int cb = 0; cb < 2; ++cb) {
            const int col = colbase + nj0 + cb * 64;
            u16* p = &out[row * HD + col];
            const ushort4 o4 = *reinterpret_cast<const ushort4*>(p);
            ushort4 y;
            y.x = f2bf(bf2f(o4.x) / (1.0f + __expf(-acc[rb*4+rr][cb*4+0])));
            y.y = f2bf(bf2f(o4.y) / (1.0f + __expf(-acc[rb*4+rr][cb*4+1])));
            y.z = f2bf(bf2f(o4.z) / (1.0f + __expf(-acc[rb*4+rr][cb*4+2])));
            y.w = f2bf(bf2f(o4.w) / (1.0f + __expf(-acc[rb*4+rr][cb*4+3])));
            *reinterpret_cast<ushort4*>(p) = y;
        }
      }
}

// ---------------------------------------------------------------------------
// Kernel 4b: Wo fp32 [k=256][c=64] -> WoT bf16 [c][k]. One block.
// ---------------------------------------------------------------------------
__global__ __launch_bounds__(256) void k_wot(
    const float* __restrict__ Wo, u16* __restrict__ WoT)
{
    const int t = threadIdx.x;
    for (int idx = t; idx < 64 * 256; idx += 256) {
        const int c = idx >> 8, k = idx & 255;
        WoT[idx] = f2bf(Wo[k * 64 + c]);
    }
}

// ---------------------------------------------------------------------------
// Kernel 5: out[row, c] = sum_hd ob[row, hd] * Wo[hd, c] — bf16 MFMA.
// Block 256 rows x 64 cols, 4 waves (wave w: rows w*64..+64, all 64 cols,
// 4x4 frags 16x16), K=256 in 4 chunks of BK=64. LDS rows 128B ([row][64k]),
// XOR swizzle key ((r&7)<<3) elems; staged via global_load_lds with
// pre-swizzled per-lane source (same G21 pattern as k_pairavg).
// ---------------------------------------------------------------------------
__global__ __launch_bounds__(256) void k_out(
    const u16* __restrict__ yb, const u16* __restrict__ WoT,
    float* __restrict__ outp)
{
    __shared__ u16 Abuf[256 * 64]; // 32KB
    __shared__ u16 Bbuf[64 * 64];  // 8KB

    const int t    = threadIdx.x;
    const int lane = t & 63, w = t >> 6;
    const size_t row0 = (size_t)blockIdx.x * 256;
    const int l3 = lane >> 3, l7 = lane & 7;
    const int esw = (l7 * 8) ^ (l3 << 3); // staging source swizzle (row&7 = l3)

    f32x4 acc[4][4];
    #pragma unroll
    for (int a = 0; a < 4; ++a)
        #pragma unroll
        for (int b = 0; b < 4; ++b)
            acc[a][b] = (f32x4){0.f, 0.f, 0.f, 0.f};

    for (int kc = 0; kc < 4; ++kc) {
        __syncthreads(); // previous chunk's reads done before overwrite
        // stage A: wave w rows [w*64, w*64+64), 8 instr x (8 rows x 128B)
        #pragma unroll
        for (int g = 0; g < 8; ++g) {
            const int rbase = w * 64 + g * 8;
            async16(&Abuf[rbase * 64],
                    &yb[(row0 + rbase + l3) * 256 + kc * 64 + esw]);
        }
        // stage B: 64 cols, 8 instr total (2 per wave)
        #pragma unroll
        for (int g = 0; g < 2; ++g) {
            const int cbase = w * 16 + g * 8;
            async16(&Bbuf[cbase * 64],
                    &WoT[(size_t)(cbase + l3) * 256 + kc * 64 + esw]);
        }
        __syncthreads(); // drains vmcnt(0)

        #pragma unroll
        for (int ks = 0; ks < 2; ++ks) {
            const int er = (ks * 32 + (lane >> 4) * 8) ^ ((lane & 7) << 3);
            s16x8 af[4], bfr[4];
            #pragma unroll
            for (int f = 0; f < 4; ++f) {
                const int r = w * 64 + f * 16 + (lane & 15); // r&7 == lane&7
                af[f] = *reinterpret_cast<const s16x8*>(&Abuf[r * 64 + er]);
                const int c = f * 16 + (lane & 15);          // c&7 == lane&7
                bfr[f] = *reinterpret_cast<const s16x8*>(&Bbuf[c * 64 + er]);
            }
            #pragma unroll
            for (int fm = 0; fm < 4; ++fm)
                #pragma unroll
                for (int fn = 0; fn < 4; ++fn)
                    acc[fm][fn] = __builtin_amdgcn_mfma_f32_16x16x32_bf16(
                        af[fm], bfr[fn], acc[fm][fn], 0, 0, 0);
        }
    }

    // C/D: col(lane&15) = c, row((lane>>4)*4+reg) = local row (m89).
    #pragma unroll
    for (int fm = 0; fm < 4; ++fm) {
        const size_t r_g = row0 + w * 64 + fm * 16 + ((lane >> 4) << 2);
        #pragma unroll
        for (int fn = 0; fn < 4; ++fn) {
            const int c = fn * 16 + (lane & 15);
            #pragma unroll
            for (int r = 0; r < 4; ++r)
                outp[(r_g + r) * 64 + c] = acc[fm][fn][r];
        }
    }
}

// ---------------------------------------------------------------------------
extern "C" void kernel_launch(void* const* d_in, const int* in_sizes, int n_in,
                              void* d_out, int out_size, void* d_ws, size_t ws_size,
                              hipStream_t stream) {
    const float* m   = (const float*)d_in[0];
    const float* z   = (const float*)d_in[1];
    const float* nmw = (const float*)d_in[2];
    const float* nmb = (const float*)d_in[3];
    const float* nzw = (const float*)d_in[4];
    const float* nzb = (const float*)d_in[5];
    const float* Wm  = (const float*)d_in[6];
    const float* Wg  = (const float*)d_in[7];
    const float* Wz  = (const float*)d_in[8];
    const float* Wo  = (const float*)d_in[9];
    float* outp = (float*)d_out;

    u16* wb  = (u16*)d_ws;                 // 8*512*512 u16   = 4MB
    u16* vbT = wb + (size_t)H * T * T;     // 256*262144 u16  = 128MB
    u16* ob  = vbT + (size_t)HD * ST;      // 262144*256 u16  = 128MB
    u16* WoT = ob + ST * HD;               // 64*256 u16      = 32KB

    k_weights<<<dim3(T),           256, 0, stream>>>(z, nzw, nzb, Wz, wb);
    k_vproj  <<<dim3(ST / 128, 2), 256, 0, stream>>>(m, nmw, nmb, Wm, vbT);
    k_pairavg<<<dim3(128, 4, 8),   256, 0, stream>>>(wb, vbT, ob);
    k_gate   <<<dim3(ST / 128, 2), 256, 0, stream>>>(m, nmw, nmb, Wg, ob);
    k_wot    <<<dim3(1),           256, 0, stream>>>(Wo, WoT);
    k_out    <<<dim3(ST / 256),    256, 0, stream>>>(ob, WoT, outp);
}